// Round 3
// baseline (722.738 us; speedup 1.0000x reference)
//
#include <hip/hip_runtime.h>
#include <hip/hip_bf16.h>
#include <cstdint>

// MHGAT: 2-layer multi-head GAT + linear skip, fp32 in/out.
// N=10000 nodes, E=160000 edges, H=4 heads.
// Layer1 (fp32 GEMM): 300 -> 512 (C=128), relu. Layer2 (bf16x3 MFMA GEMM): 512 -> 2048 (C=512).

__device__ __forceinline__ float lrelu(float v) { return v >= 0.f ? v : 0.2f * v; }

// bf16 bit helpers (RNE), avoids __hip_bfloat16 API differences
__device__ __forceinline__ short f2bf(float x) {
  unsigned u = __float_as_uint(x);
  unsigned r = (u + 0x7fffu + ((u >> 16) & 1u)) >> 16;
  return (short)r;
}
__device__ __forceinline__ float bf2f(short b) {
  return __uint_as_float(((unsigned)(unsigned short)b) << 16);
}

typedef __attribute__((ext_vector_type(8))) short bf16x8;
typedef __attribute__((ext_vector_type(4))) float f32x4;

__device__ __forceinline__ void gload_lds16(const void* g, void* l) {
  // CK-style addrspace casts; LDS dest = wave-uniform base + lane*16 (m104)
  auto gp = (const __attribute__((address_space(1))) unsigned int*)(uintptr_t)g;
  auto lp = (__attribute__((address_space(3))) unsigned int*)(uintptr_t)l;
  __builtin_amdgcn_global_load_lds(gp, lp, 16, 0, 0);
}

// ---------------- CSR build (group edges by destination) ----------------
__global__ void count_edges_k(const int* __restrict__ dstv, int* __restrict__ counts, int E) {
  int e = blockIdx.x * 256 + threadIdx.x;
  if (e < E) atomicAdd(&counts[dstv[e]], 1);
}

// single-block exclusive scan over N counts; wave shfl scan, 2 barriers/chunk
__global__ void scan_k(const int* __restrict__ counts, int* __restrict__ rowptr,
                       int* __restrict__ cursor, int n) {
  __shared__ int wsum[16];
  __shared__ int s_base;
  int tid = threadIdx.x, lane = tid & 63, wv = tid >> 6;
  if (tid == 0) s_base = 0;
  __syncthreads();
  for (int base = 0; base < n; base += 1024) {
    int i = base + tid;
    int v = (i < n) ? counts[i] : 0;
    int x = v;  // inclusive wave scan
#pragma unroll
    for (int off = 1; off < 64; off <<= 1) {
      int t = __shfl_up(x, off);
      if (lane >= off) x += t;
    }
    if (lane == 63) wsum[wv] = x;
    __syncthreads();
    int woff = 0, tot = 0;
#pragma unroll
    for (int w = 0; w < 16; ++w) {
      int s = wsum[w];
      tot += s;
      if (w < wv) woff += s;
    }
    int b = s_base;
    if (i < n) {
      int excl = b + woff + x - v;
      rowptr[i] = excl;
      cursor[i] = excl;
    }
    __syncthreads();
    if (tid == 0) s_base = b + tot;
  }
  __syncthreads();
  if (tid == 0) rowptr[n] = s_base;
}

__global__ void fill_csr_k(const int* __restrict__ srcv, const int* __restrict__ dstv,
                           int* __restrict__ cursor, int* __restrict__ csr_src, int E) {
  int e = blockIdx.x * 256 + threadIdx.x;
  if (e < E) {
    int p = atomicAdd(&cursor[dstv[e]], 1);
    csr_src[p] = srcv[e];
  }
}

// ---------------- fp32 tiled GEMM 64x64 (layer 1; K=300) ----------------
template <bool BIAS>
__global__ __launch_bounds__(256) void gemm_k(
    const float* __restrict__ A, const float* __restrict__ B,
    const float* __restrict__ bias, float* __restrict__ C,
    int M, int N, int K) {
  constexpr int BK = 16;
  __shared__ float As[BK][68];
  __shared__ float Bs[BK][64];
  int tid = threadIdx.x;
  int tx = tid & 15, ty = tid >> 4;
  int m0 = blockIdx.y * 64, n0 = blockIdx.x * 64;
  float acc[4][4] = {};
  int arow = tid >> 2, akq = (tid & 3) * 4;
  int bk = tid >> 4, bnq = (tid & 15) * 4;

  for (int k0 = 0; k0 < K; k0 += BK) {
    float4 av;
    int gm = m0 + arow, gk = k0 + akq;
    if (gm < M && gk + 3 < K) {
      av = *(const float4*)(A + (size_t)gm * K + gk);
    } else {
      av.x = (gm < M && gk + 0 < K) ? A[(size_t)gm * K + gk + 0] : 0.f;
      av.y = (gm < M && gk + 1 < K) ? A[(size_t)gm * K + gk + 1] : 0.f;
      av.z = (gm < M && gk + 2 < K) ? A[(size_t)gm * K + gk + 2] : 0.f;
      av.w = (gm < M && gk + 3 < K) ? A[(size_t)gm * K + gk + 3] : 0.f;
    }
    float4 bv = make_float4(0.f, 0.f, 0.f, 0.f);
    int gbk = k0 + bk;
    if (gbk < K) bv = *(const float4*)(B + (size_t)gbk * N + n0 + bnq);

    As[akq + 0][arow] = av.x;
    As[akq + 1][arow] = av.y;
    As[akq + 2][arow] = av.z;
    As[akq + 3][arow] = av.w;
    *(float4*)&Bs[bk][bnq] = bv;
    __syncthreads();

#pragma unroll
    for (int kk = 0; kk < BK; ++kk) {
      float4 a4 = *(const float4*)&As[kk][ty * 4];
      float4 b4 = *(const float4*)&Bs[kk][tx * 4];
      float a[4] = {a4.x, a4.y, a4.z, a4.w};
      float b[4] = {b4.x, b4.y, b4.z, b4.w};
#pragma unroll
      for (int i = 0; i < 4; ++i)
#pragma unroll
        for (int j = 0; j < 4; ++j) acc[i][j] = fmaf(a[i], b[j], acc[i][j]);
    }
    __syncthreads();
  }

#pragma unroll
  for (int i = 0; i < 4; ++i) {
    int gm = m0 + ty * 4 + i;
    if (gm >= M) continue;
    float4 o;
    float bx = 0.f, by = 0.f, bz = 0.f, bw = 0.f;
    if (BIAS) {
      bx = bias[n0 + tx * 4 + 0];
      by = bias[n0 + tx * 4 + 1];
      bz = bias[n0 + tx * 4 + 2];
      bw = bias[n0 + tx * 4 + 3];
    }
    o.x = acc[i][0] + bx;
    o.y = acc[i][1] + by;
    o.z = acc[i][2] + bz;
    o.w = acc[i][3] + bw;
    *(float4*)(C + (size_t)gm * N + n0 + tx * 4) = o;
  }
}

// ---------------- weight transpose + bf16 split: W[K,Nn] -> Wt{h,l}[Nn,K] ----------------
// K must be 512 here (bit tricks).
__global__ void wsplit_t_k(const float* __restrict__ W, short* __restrict__ Wth,
                           short* __restrict__ Wtl, int Nn) {
  int idx = blockIdx.x * 256 + threadIdx.x;  // idx = n*512 + k
  if (idx >= Nn * 512) return;
  int k = idx & 511;
  int n = idx >> 9;
  float a = W[(size_t)k * Nn + n];
  short h = f2bf(a);
  Wth[idx] = h;
  Wtl[idx] = f2bf(a - bf2f(h));
}

// ---------------- bf16x3 split-MFMA GEMM: C = A@B (+bias) ----------------
// A given as bf16 split pair Ah/Al [M,K] row-major; B as transposed split
// Bh/Bl [Nn,K] row-major. K%32==0, Nn%128==0. 128x128 tile, 4 waves,
// 64x64/wave = 4x4 frags of 16x16, BK=32, global_load_lds staging (m97 pattern).
template <bool BIAS>
__global__ __launch_bounds__(256) void gemm_bf16x3_k(
    const short* __restrict__ Ah, const short* __restrict__ Al,
    const short* __restrict__ Bh, const short* __restrict__ Bl,
    const float* __restrict__ bias, float* __restrict__ C,
    int M, int Nn, int K) {
  __shared__ __align__(16) short Ash[128 * 32];
  __shared__ __align__(16) short Asl[128 * 32];
  __shared__ __align__(16) short Bsh[128 * 32];
  __shared__ __align__(16) short Bsl[128 * 32];
  int tid = threadIdx.x, w = tid >> 6, l = tid & 63;
  int m0 = blockIdx.y * 128, n0 = blockIdx.x * 128;
  int wm = (w >> 1) * 64, wn = (w & 1) * 64;

  f32x4 acc[4][4] = {};  // [mi][ni]

  // staging: wave w stages rows [w*32, w*32+32) of each 128x32 tile, 2 issues each.
  // issue covers 16 rows: lane l -> row l>>2, k elem (l&3)*8  (linear lane*16B order)
  int r_in = l >> 2;
  int kq = (l & 3) * 8;
  int arow_base = m0 + w * 32 + r_in;
  int brow_base = n0 + w * 32 + r_in;
  int lbase = (w * 32) * 32;  // lds elem base, issue i adds 16*32

  int fr = l & 15, fk = (l >> 4) * 8;  // fragment lane geometry (A row / B col = fr)

  for (int k0 = 0; k0 < K; k0 += 32) {
    __syncthreads();  // prior MFMA frag reads done before overwrite
#pragma unroll
    for (int i = 0; i < 2; ++i) {
      int am = min(arow_base + i * 16, M - 1);  // clamp; dup rows discarded at store
      int bn = brow_base + i * 16;
      size_t aoff = (size_t)am * K + k0 + kq;
      size_t boff = (size_t)bn * K + k0 + kq;
      int lofs = lbase + i * (16 * 32);
      gload_lds16(Ah + aoff, &Ash[lofs]);
      gload_lds16(Al + aoff, &Asl[lofs]);
      gload_lds16(Bh + boff, &Bsh[lofs]);
      gload_lds16(Bl + boff, &Bsl[lofs]);
    }
    __syncthreads();  // drains vmcnt(0): staged data visible

    bf16x8 afh[4], afl[4], bfh[4], bfl[4];
#pragma unroll
    for (int t = 0; t < 4; ++t) {
      int ar = wm + t * 16 + fr;
      afh[t] = *(const bf16x8*)&Ash[ar * 32 + fk];
      afl[t] = *(const bf16x8*)&Asl[ar * 32 + fk];
      int br = wn + t * 16 + fr;
      bfh[t] = *(const bf16x8*)&Bsh[br * 32 + fk];
      bfl[t] = *(const bf16x8*)&Bsl[br * 32 + fk];
    }
#pragma unroll
    for (int mi = 0; mi < 4; ++mi)
#pragma unroll
      for (int ni = 0; ni < 4; ++ni) {
        acc[mi][ni] = __builtin_amdgcn_mfma_f32_16x16x32_bf16(afh[mi], bfh[ni], acc[mi][ni], 0, 0, 0);
        acc[mi][ni] = __builtin_amdgcn_mfma_f32_16x16x32_bf16(afh[mi], bfl[ni], acc[mi][ni], 0, 0, 0);
        acc[mi][ni] = __builtin_amdgcn_mfma_f32_16x16x32_bf16(afl[mi], bfh[ni], acc[mi][ni], 0, 0, 0);
      }
  }

  // C/D layout (m89/m91 verified): col = lane&15, row = (lane>>4)*4 + reg
  int fq = (l >> 4) * 4;
#pragma unroll
  for (int ni = 0; ni < 4; ++ni) {
    int gc = n0 + wn + ni * 16 + fr;
    float bv = BIAS ? bias[gc] : 0.f;
#pragma unroll
    for (int mi = 0; mi < 4; ++mi) {
      int grb = m0 + wm + mi * 16 + fq;
#pragma unroll
      for (int r = 0; r < 4; ++r) {
        int gr = grb + r;
        if (gr < M) C[(size_t)gr * Nn + gc] = acc[mi][ni][r] + bv;
      }
    }
  }
}

// ---------------- attention coefficients: al_s/al_d [N,H] ----------------
template <int C>
__global__ __launch_bounds__(256) void att_coef_k(
    const float* __restrict__ hfeat, const float* __restrict__ a_src,
    const float* __restrict__ a_dst, float* __restrict__ al_s,
    float* __restrict__ al_d, int n) {
  int wave = threadIdx.x >> 6, lane = threadIdx.x & 63;
  int node = blockIdx.x * 4 + wave;
  if (node >= n) return;
  constexpr int F = 4 * C;
  const float* hrow = hfeat + (size_t)node * F;
  float s[4] = {0, 0, 0, 0}, d[4] = {0, 0, 0, 0};
  for (int f = lane; f < F; f += 64) {
    float hv = hrow[f];
    int h = f / C;
    s[h] = fmaf(hv, a_src[f], s[h]);
    d[h] = fmaf(hv, a_dst[f], d[h]);
  }
#pragma unroll
  for (int off = 32; off; off >>= 1) {
#pragma unroll
    for (int h = 0; h < 4; ++h) {
      s[h] += __shfl_xor(s[h], off);
      d[h] += __shfl_xor(d[h], off);
    }
  }
  if (lane == 0) {
#pragma unroll
    for (int h = 0; h < 4; ++h) {
      al_s[node * 4 + h] = s[h];
      al_d[node * 4 + h] = d[h];
    }
  }
}

// ---------------- per-dst-node softmax + weighted aggregation ----------------
// result = softmax-aggregate + bias + skip[n,:]; SPLIT: write bf16 split pair
// (layer-1, feeds MFMA GEMM); else write fp32 to out.
template <int F, int C, bool RELU, bool SPLIT>
__global__ __launch_bounds__(256) void gat_aggregate_k(
    const float* __restrict__ hfeat, const float* __restrict__ al_s,
    const float* __restrict__ al_d, const int* __restrict__ rowptr,
    const int* __restrict__ csr_src, const float* __restrict__ bias,
    const float* __restrict__ skip, float* __restrict__ out,
    short* __restrict__ oh, short* __restrict__ ol) {
  constexpr int NF = F / 256;
  int n = blockIdx.x;
  int tid = threadIdx.x;
  int lane = tid & 63, wave = tid >> 6;
  int r0 = rowptr[n], r1 = rowptr[n + 1];

  float ald[4];
#pragma unroll
  for (int h = 0; h < 4; ++h) ald[h] = al_d[n * 4 + h];

  __shared__ float red[4][4];
  __shared__ int src_sh[64];
  __shared__ float w_sh[64][4];

  // Phase 1: per-head max of leaky_relu(al_s[src]+al_d[n])
  float m[4] = {-3.4e38f, -3.4e38f, -3.4e38f, -3.4e38f};
  for (int e = r0 + tid; e < r1; e += 256) {
    int s = csr_src[e];
#pragma unroll
    for (int h = 0; h < 4; ++h) m[h] = fmaxf(m[h], lrelu(al_s[s * 4 + h] + ald[h]));
  }
#pragma unroll
  for (int off = 32; off; off >>= 1)
#pragma unroll
    for (int h = 0; h < 4; ++h) m[h] = fmaxf(m[h], __shfl_xor(m[h], off));
  if (lane == 0)
#pragma unroll
    for (int h = 0; h < 4; ++h) red[wave][h] = m[h];
  __syncthreads();
#pragma unroll
  for (int h = 0; h < 4; ++h)
    m[h] = fmaxf(fmaxf(red[0][h], red[1][h]), fmaxf(red[2][h], red[3][h]));
  __syncthreads();

  // Phase 2: denominator
  float den[4] = {0, 0, 0, 0};
  for (int e = r0 + tid; e < r1; e += 256) {
    int s = csr_src[e];
#pragma unroll
    for (int h = 0; h < 4; ++h) den[h] += expf(lrelu(al_s[s * 4 + h] + ald[h]) - m[h]);
  }
#pragma unroll
  for (int off = 32; off; off >>= 1)
#pragma unroll
    for (int h = 0; h < 4; ++h) den[h] += __shfl_xor(den[h], off);
  if (lane == 0)
#pragma unroll
    for (int h = 0; h < 4; ++h) red[wave][h] = den[h];
  __syncthreads();
  float rden[4];
#pragma unroll
  for (int h = 0; h < 4; ++h) {
    float dsum = red[0][h] + red[1][h] + red[2][h] + red[3][h];
    rden[h] = 1.f / fmaxf(dsum, 1e-16f);
  }

  // Phase 3: weighted gather of source features, 64-edge chunks
  float acc[NF] = {};
  for (int cs = r0; cs < r1; cs += 64) {
    int ce = min(64, r1 - cs);
    __syncthreads();
    if (tid < ce) src_sh[tid] = csr_src[cs + tid];
    if (tid < ce * 4) {
      int j = tid >> 2, h = tid & 3;
      int s = csr_src[cs + j];
      w_sh[j][h] = expf(lrelu(al_s[s * 4 + h] + ald[h]) - m[h]) * rden[h];
    }
    __syncthreads();
    for (int j = 0; j < ce; ++j) {
      int s = src_sh[j];
      const float* hrow = hfeat + (size_t)s * F;
#pragma unroll
      for (int i = 0; i < NF; ++i) {
        int f = tid + i * 256;
        acc[i] = fmaf(w_sh[j][f / C], hrow[f], acc[i]);
      }
    }
  }

  // Epilogue: + bias + skip, optional relu, fp32 or bf16-split write
  size_t rowoff = (size_t)n * F;
#pragma unroll
  for (int i = 0; i < NF; ++i) {
    int f = tid + i * 256;
    float v = acc[i] + bias[f] + skip[rowoff + f];
    if (RELU) v = fmaxf(v, 0.f);
    if (SPLIT) {
      short h = f2bf(v);
      oh[rowoff + f] = h;
      ol[rowoff + f] = f2bf(v - bf2f(h));
    } else {
      out[rowoff + f] = v;
    }
  }
}

extern "C" void kernel_launch(void* const* d_in, const int* in_sizes, int n_in,
                              void* d_out, int out_size, void* d_ws, size_t ws_size,
                              hipStream_t stream) {
  (void)n_in; (void)out_size; (void)ws_size;
  const float* x   = (const float*)d_in[0];
  const int*   ei  = (const int*)d_in[1];
  const float* W1  = (const float*)d_in[2];
  const float* as1 = (const float*)d_in[3];
  const float* ad1 = (const float*)d_in[4];
  const float* b1  = (const float*)d_in[5];
  const float* Wl1 = (const float*)d_in[6];
  const float* bl1 = (const float*)d_in[7];
  const float* W2  = (const float*)d_in[8];
  const float* as2 = (const float*)d_in[9];
  const float* ad2 = (const float*)d_in[10];
  const float* b2  = (const float*)d_in[11];
  const float* Wl2 = (const float*)d_in[12];
  const float* bl2 = (const float*)d_in[13];

  const int N = 10000;
  const int E = in_sizes[1] / 2;
  const int* srcv = ei;
  const int* dstv = ei + E;

  // ---- workspace layout (~112 MB) ----
  char* p = (char*)d_ws;
  float* hfeat = (float*)p; p += (size_t)N * 2048 * 4;  // layer2 attn feats; layer1 uses
  float* s1 = hfeat + (size_t)N * 512;                  //   [0,512)=feats, [512,1024)=skip
  short* h1h = (short*)p; p += (size_t)N * 512 * 2;
  short* h1l = (short*)p; p += (size_t)N * 512 * 2;
  short* w2ht = (short*)p; p += (size_t)2048 * 512 * 2;
  short* w2lt = (short*)p; p += (size_t)2048 * 512 * 2;
  short* wl2ht = (short*)p; p += (size_t)2048 * 512 * 2;
  short* wl2lt = (short*)p; p += (size_t)2048 * 512 * 2;
  float* als = (float*)p; p += (size_t)N * 4 * 4;
  float* ald = (float*)p; p += (size_t)N * 4 * 4;
  int* rowptr = (int*)p; p += (N + 1) * 4;
  int* cursor = (int*)p; p += N * 4;
  int* counts = (int*)p; p += N * 4;
  int* csr_src = (int*)p; p += (size_t)E * 4;

  // ---- CSR build (recomputed every call) ----
  hipMemsetAsync(counts, 0, N * sizeof(int), stream);
  count_edges_k<<<(E + 255) / 256, 256, 0, stream>>>(dstv, counts, E);
  scan_k<<<1, 1024, 0, stream>>>(counts, rowptr, cursor, N);
  fill_csr_k<<<(E + 255) / 256, 256, 0, stream>>>(srcv, dstv, cursor, csr_src, E);

  // ---- weight transpose+split for layer-2 MFMA GEMMs (K=512) ----
  wsplit_t_k<<<(2048 * 512 + 255) / 256, 256, 0, stream>>>(W2, w2ht, w2lt, 2048);
  wsplit_t_k<<<(2048 * 512 + 255) / 256, 256, 0, stream>>>(Wl2, wl2ht, wl2lt, 2048);

  // ---- Layer 1: 300 -> 512 (fp32 GEMMs), relu; epilogue emits bf16 split h1 ----
  gemm_k<false><<<dim3(8, (N + 63) / 64), 256, 0, stream>>>(x, W1, nullptr, hfeat, N, 512, 300);
  gemm_k<true><<<dim3(8, (N + 63) / 64), 256, 0, stream>>>(x, Wl1, bl1, s1, N, 512, 300);
  att_coef_k<128><<<(N + 3) / 4, 256, 0, stream>>>(hfeat, as1, ad1, als, ald, N);
  gat_aggregate_k<512, 128, true, true><<<N, 256, 0, stream>>>(
      hfeat, als, ald, rowptr, csr_src, b1, s1, nullptr, h1h, h1l);

  // ---- Layer 2: 512 -> 2048 (bf16x3 MFMA GEMMs) ----
  gemm_bf16x3_k<false><<<dim3(2048 / 128, (N + 127) / 128), 256, 0, stream>>>(
      h1h, h1l, w2ht, w2lt, nullptr, hfeat, N, 2048, 512);
  gemm_bf16x3_k<true><<<dim3(2048 / 128, (N + 127) / 128), 256, 0, stream>>>(
      h1h, h1l, wl2ht, wl2lt, bl2, (float*)d_out, N, 2048, 512);
  att_coef_k<512><<<(N + 3) / 4, 256, 0, stream>>>(hfeat, as2, ad2, als, ald, N);
  gat_aggregate_k<2048, 512, false, false><<<N, 256, 0, stream>>>(
      hfeat, als, ald, rowptr, csr_src, b2, (float*)d_out, (float*)d_out, nullptr, nullptr);
}